// Round 4
// baseline (220.543 us; speedup 1.0000x reference)
//
#include <hip/hip_runtime.h>

// GraphPooling: B=8, N=3072, D=1024, POOL=3, steps=1024
//  out[b, 2k,   d] = (sum x[b, s..e, d]) / (e-s+1) + 0.006
//  out[b, 2k+1, d] = mean(x[b, 3k:3k+3, d])
//
// Round-4: same window-granularity hierarchy as R3, but tuned for occupancy:
//  K1: CHW=4 windows/chunk -> 2048 blocks (32 waves/CU).
//  K3: KT=8 steps/block    -> 1024 blocks (16 waves/CU) for the gather.
// All accesses float4 (16 B/lane), all rows fully coalesced 4 KB.

constexpr int Bdim  = 8;
constexpr int Nn    = 3072;
constexpr int Dd    = 1024;
constexpr int STEPS = 1024;   // windows
constexpr int CHW   = 4;      // windows per chunk
constexpr int NCH   = 256;    // STEPS / CHW
constexpr int KT    = 8;      // steps per K3 block
constexpr int NKT   = 128;    // STEPS / KT
constexpr int D4    = Dd / 4; // 256 float4 per row
constexpr float EPS = 0.006f;

constexpr size_t WL_E = (size_t)Bdim * STEPS * Dd;        // 32 MB
constexpr size_t P_E  = (size_t)Bdim * NCH * Dd;          //  8 MB
constexpr size_t O_E  = (size_t)Bdim * (NCH + 1) * Dd;    //  8.4 MB

__device__ __forceinline__ float4 f4add(float4 a, float4 b) {
    return make_float4(a.x + b.x, a.y + b.y, a.z + b.z, a.w + b.w);
}

// ---------------- K1: window sums + within-chunk prefix ----------------
__global__ __launch_bounds__(256)
void k1_scan(const float4* __restrict__ x4, float4* __restrict__ out4,
             float4* __restrict__ Wl4, float4* __restrict__ P4) {
    const int t  = threadIdx.x;          // float4 column 0..255
    const int ch = blockIdx.x;           // 0..255
    const int b  = blockIdx.y;           // 0..7
    const int k0 = ch * CHW;             // first window of chunk
    const int r0 = k0 * 3;               // first row of chunk

    const float4* xp = x4   + ((size_t)(b * Nn + r0)) * D4 + t;
    float4*       wl = Wl4  + ((size_t)(b * STEPS + k0)) * D4 + t;
    float4*       op = out4 + ((size_t)b * 2 * STEPS) * D4 + t;

    float4 run = make_float4(0.f, 0.f, 0.f, 0.f);
#pragma unroll
    for (int w = 0; w < CHW; ++w) {
        wl[(size_t)w * D4] = run;                       // exclusive prefix
        float4 v0 = xp[(size_t)(3 * w + 0) * D4];
        float4 v1 = xp[(size_t)(3 * w + 1) * D4];
        float4 v2 = xp[(size_t)(3 * w + 2) * D4];
        float4 s3 = f4add(f4add(v0, v1), v2);
        float4 wm = make_float4(s3.x * (1.f / 3.f), s3.y * (1.f / 3.f),
                                s3.z * (1.f / 3.f), s3.w * (1.f / 3.f));
        op[(size_t)(2 * (k0 + w) + 1) * D4] = wm;       // odd output row
        run = f4add(run, s3);
    }
    P4[((size_t)b * NCH + ch) * D4 + t] = run;
}

// ---------------- K2: scan chunk totals -> exclusive chunk prefix ----------------
__global__ __launch_bounds__(128)
void k2_chscan(const float* __restrict__ P, float* __restrict__ O) {
    const int d = blockIdx.x * 128 + threadIdx.x;   // 8 tiles of 128 cols
    const int b = blockIdx.y;
    const float* p = P + (size_t)b * NCH * Dd + d;
    float*       o = O + (size_t)b * (NCH + 1) * Dd + d;
    float run = 0.f;
#pragma unroll 8
    for (int ch = 0; ch < NCH; ++ch) {
        o[(size_t)ch * Dd] = run;
        run += p[(size_t)ch * Dd];
    }
    o[(size_t)NCH * Dd] = run;                      // total = c[N]
}

// ---------------- K3: gather segment means ----------------
__global__ __launch_bounds__(256)
void k3_gather(const float4* __restrict__ x4, const float4* __restrict__ Wl4,
               const float4* __restrict__ O4, const int* __restrict__ graph,
               float4* __restrict__ out4) {
    __shared__ int gbuf[2 * KT];
    const int t  = threadIdx.x;
    const int kt = blockIdx.x;
    const int b  = blockIdx.y;

    const int* gs = graph + ((size_t)(b * STEPS + kt * KT)) * 2;
    if (t < 2 * KT) gbuf[t] = gs[t];
    __syncthreads();

    const float4* xb = x4  + (size_t)b * Nn * D4 + t;
    const float4* wl = Wl4 + (size_t)b * STEPS * D4 + t;
    const float4* oc = O4  + (size_t)b * (NCH + 1) * D4 + t;
    float4*       ob = out4 + (size_t)b * 2 * STEPS * D4 + t;

#pragma unroll
    for (int j = 0; j < KT; ++j) {
        int s = gbuf[2 * j];
        int e = gbuf[2 * j + 1];

        int m1 = s / 3, r1 = s - 3 * m1;            // s <= N-1 -> m1 <= 1023
        float4 cs = f4add(oc[(size_t)(m1 >> 2) * D4], wl[(size_t)m1 * D4]);
        if (r1 > 0) cs = f4add(cs, xb[(size_t)(3 * m1) * D4]);
        if (r1 > 1) cs = f4add(cs, xb[(size_t)(3 * m1 + 1) * D4]);

        int ie = e + 1;                             // 1..N
        float4 ce;
        if (ie == Nn) {
            ce = oc[(size_t)NCH * D4];
        } else {
            int m2 = ie / 3, r2 = ie - 3 * m2;
            ce = f4add(oc[(size_t)(m2 >> 2) * D4], wl[(size_t)m2 * D4]);
            if (r2 > 0) ce = f4add(ce, xb[(size_t)(3 * m2) * D4]);
            if (r2 > 1) ce = f4add(ce, xb[(size_t)(3 * m2 + 1) * D4]);
        }

        float inv = 1.f / (float)(e - s + 1);
        float4 res = make_float4((ce.x - cs.x) * inv + EPS,
                                 (ce.y - cs.y) * inv + EPS,
                                 (ce.z - cs.z) * inv + EPS,
                                 (ce.w - cs.w) * inv + EPS);
        int k = kt * KT + j;
        ob[(size_t)(2 * k) * D4] = res;             // even output row
    }
}

extern "C" void kernel_launch(void* const* d_in, const int* in_sizes, int n_in,
                              void* d_out, int out_size, void* d_ws, size_t ws_size,
                              hipStream_t stream) {
    const float* x     = (const float*)d_in[0];
    const int*   graph = (const int*)d_in[1];
    float*       out   = (float*)d_out;

    float* Wl = (float*)d_ws;
    float* P  = Wl + WL_E;
    float* O  = P + P_E;

    dim3 g1(NCH, Bdim);          // (256, 8) = 2048 blocks -> 8 blocks/CU
    k1_scan<<<g1, 256, 0, stream>>>((const float4*)x, (float4*)out,
                                    (float4*)Wl, (float4*)P);
    dim3 g2(Dd / 128, Bdim);     // (8, 8) = 64 blocks
    k2_chscan<<<g2, 128, 0, stream>>>(P, O);
    dim3 g3(NKT, Bdim);          // (128, 8) = 1024 blocks -> 4 blocks/CU
    k3_gather<<<g3, 256, 0, stream>>>((const float4*)x, (const float4*)Wl,
                                      (const float4*)O, graph, (float4*)out);
}

// Round 6
// 202.998 us; speedup vs baseline: 1.0864x; 1.0864x over previous
//
#include <hip/hip_runtime.h>

// GraphPooling: B=8, N=3072, D=1024, POOL=3, steps=1024
//  out[b, 2k,   d] = (sum x[b, s..e, d]) / (e-s+1) + 0.006
//  out[b, 2k+1, d] = mean(x[b, 3k:3k+3, d])
//
// Round-6 (= R5 with compile fix): R3 hierarchy (CHW=8, NCH=128) with
//  - K2 rewritten as 2-level float4 scan (serial depth 128 -> 16+8)
//  - K3 KT=8 (16 waves/CU for the gather)
//  - nontemporal final-output stores via native vector type (preserve L3
//    for x/Wl; __builtin_nontemporal_store rejects HIP_vector_type)

constexpr int Bdim  = 8;
constexpr int Nn    = 3072;
constexpr int Dd    = 1024;
constexpr int STEPS = 1024;   // windows
constexpr int CHW   = 8;      // windows per chunk
constexpr int NCH   = 128;    // STEPS / CHW
constexpr int KT    = 8;      // steps per K3 block
constexpr int NKT   = 128;    // STEPS / KT
constexpr int D4    = Dd / 4; // 256 float4 per row
constexpr float EPS = 0.006f;

constexpr size_t WL_E = (size_t)Bdim * STEPS * Dd;        // 32 MB
constexpr size_t P_E  = (size_t)Bdim * NCH * Dd;          //  4 MB

typedef float nat_f4 __attribute__((ext_vector_type(4)));

__device__ __forceinline__ float4 f4add(float4 a, float4 b) {
    return make_float4(a.x + b.x, a.y + b.y, a.z + b.z, a.w + b.w);
}

__device__ __forceinline__ void nt_store(float4 v, float4* p) {
    nat_f4 nv = {v.x, v.y, v.z, v.w};
    __builtin_nontemporal_store(nv, reinterpret_cast<nat_f4*>(p));
}

// ---------------- K1: window sums + within-chunk prefix ----------------
__global__ __launch_bounds__(256)
void k1_scan(const float4* __restrict__ x4, float4* __restrict__ out4,
             float4* __restrict__ Wl4, float4* __restrict__ P4) {
    const int t  = threadIdx.x;          // float4 column 0..255
    const int ch = blockIdx.x;           // 0..127
    const int b  = blockIdx.y;           // 0..7
    const int k0 = ch * CHW;
    const int r0 = k0 * 3;

    const float4* xp = x4   + ((size_t)(b * Nn + r0)) * D4 + t;
    float4*       wl = Wl4  + ((size_t)(b * STEPS + k0)) * D4 + t;
    float4*       op = out4 + ((size_t)b * 2 * STEPS) * D4 + t;

    float4 run = make_float4(0.f, 0.f, 0.f, 0.f);
#pragma unroll
    for (int w = 0; w < CHW; ++w) {
        wl[(size_t)w * D4] = run;                       // exclusive prefix
        float4 v0 = xp[(size_t)(3 * w + 0) * D4];
        float4 v1 = xp[(size_t)(3 * w + 1) * D4];
        float4 v2 = xp[(size_t)(3 * w + 2) * D4];
        float4 s3 = f4add(f4add(v0, v1), v2);
        float4 wm = make_float4(s3.x * (1.f / 3.f), s3.y * (1.f / 3.f),
                                s3.z * (1.f / 3.f), s3.w * (1.f / 3.f));
        nt_store(wm, &op[(size_t)(2 * (k0 + w) + 1) * D4]);  // odd output row
        run = f4add(run, s3);
    }
    P4[((size_t)b * NCH + ch) * D4 + t] = run;
}

// ---------------- K2: 2-level scan of chunk totals -> exclusive prefix O ----
__global__ __launch_bounds__(256)
void k2_chscan(const float4* __restrict__ P4, float4* __restrict__ O4) {
    __shared__ float4 part[8][33];
    const int cw  = threadIdx.x & 31;          // f4-col within tile
    const int seg = threadIdx.x >> 5;          // 0..7 -> 16 chunks each
    const int col = blockIdx.x * 32 + cw;
    const int b   = blockIdx.y;

    const float4* p = P4 + (size_t)b * NCH * D4 + col;
    float4 v[16];
    float4 sum = make_float4(0.f, 0.f, 0.f, 0.f);
#pragma unroll
    for (int i = 0; i < 16; ++i) {
        v[i] = p[(size_t)(seg * 16 + i) * D4];
        sum = f4add(sum, v[i]);
    }
    part[seg][cw] = sum;
    __syncthreads();
    if (threadIdx.x < 32) {
        float4 run = make_float4(0.f, 0.f, 0.f, 0.f);
#pragma unroll
        for (int s = 0; s < 8; ++s) {
            float4 t2 = part[s][threadIdx.x];
            part[s][threadIdx.x] = run;
            run = f4add(run, t2);
        }
    }
    __syncthreads();
    float4 run = part[seg][cw];
    float4* o = O4 + (size_t)b * (NCH + 1) * D4 + col;
#pragma unroll
    for (int i = 0; i < 16; ++i) {
        o[(size_t)(seg * 16 + i) * D4] = run;
        run = f4add(run, v[i]);
    }
    if (seg == 7) o[(size_t)NCH * D4] = run;   // grand total = c[N]
}

// ---------------- K3: gather segment means ----------------
__global__ __launch_bounds__(256)
void k3_gather(const float4* __restrict__ x4, const float4* __restrict__ Wl4,
               const float4* __restrict__ O4, const int* __restrict__ graph,
               float4* __restrict__ out4) {
    __shared__ int gbuf[2 * KT];
    const int t  = threadIdx.x;
    const int kt = blockIdx.x;
    const int b  = blockIdx.y;

    const int* gs = graph + ((size_t)(b * STEPS + kt * KT)) * 2;
    if (t < 2 * KT) gbuf[t] = gs[t];
    __syncthreads();

    const float4* xb = x4  + (size_t)b * Nn * D4 + t;
    const float4* wl = Wl4 + (size_t)b * STEPS * D4 + t;
    const float4* oc = O4  + (size_t)b * (NCH + 1) * D4 + t;
    float4*       ob = out4 + (size_t)b * 2 * STEPS * D4 + t;

#pragma unroll
    for (int j = 0; j < KT; ++j) {
        int s = gbuf[2 * j];
        int e = gbuf[2 * j + 1];

        int m1 = s / 3, r1 = s - 3 * m1;            // m1 <= 1023
        float4 cs = f4add(oc[(size_t)(m1 >> 3) * D4], wl[(size_t)m1 * D4]);
        if (r1 > 0) cs = f4add(cs, xb[(size_t)(3 * m1) * D4]);
        if (r1 > 1) cs = f4add(cs, xb[(size_t)(3 * m1 + 1) * D4]);

        int ie = e + 1;                             // 1..N
        float4 ce;
        if (ie == Nn) {
            ce = oc[(size_t)NCH * D4];
        } else {
            int m2 = ie / 3, r2 = ie - 3 * m2;
            ce = f4add(oc[(size_t)(m2 >> 3) * D4], wl[(size_t)m2 * D4]);
            if (r2 > 0) ce = f4add(ce, xb[(size_t)(3 * m2) * D4]);
            if (r2 > 1) ce = f4add(ce, xb[(size_t)(3 * m2 + 1) * D4]);
        }

        float inv = 1.f / (float)(e - s + 1);
        float4 res = make_float4((ce.x - cs.x) * inv + EPS,
                                 (ce.y - cs.y) * inv + EPS,
                                 (ce.z - cs.z) * inv + EPS,
                                 (ce.w - cs.w) * inv + EPS);
        int k = kt * KT + j;
        nt_store(res, &ob[(size_t)(2 * k) * D4]);   // even output row
    }
}

extern "C" void kernel_launch(void* const* d_in, const int* in_sizes, int n_in,
                              void* d_out, int out_size, void* d_ws, size_t ws_size,
                              hipStream_t stream) {
    const float* x     = (const float*)d_in[0];
    const int*   graph = (const int*)d_in[1];
    float*       out   = (float*)d_out;

    float* Wl = (float*)d_ws;
    float* P  = Wl + WL_E;
    float* O  = P + P_E;

    dim3 g1(NCH, Bdim);          // (128, 8) = 1024 blocks
    k1_scan<<<g1, 256, 0, stream>>>((const float4*)x, (float4*)out,
                                    (float4*)Wl, (float4*)P);
    dim3 g2(D4 / 32, Bdim);      // (8, 8) = 64 blocks
    k2_chscan<<<g2, 256, 0, stream>>>((const float4*)P, (float4*)O);
    dim3 g3(NKT, Bdim);          // (128, 8) = 1024 blocks
    k3_gather<<<g3, 256, 0, stream>>>((const float4*)x, (const float4*)Wl,
                                      (const float4*)O, graph, (float4*)out);
}

// Round 7
// 197.667 us; speedup vs baseline: 1.1157x; 1.0270x over previous
//
#include <hip/hip_runtime.h>

// GraphPooling: B=8, N=3072, D=1024, POOL=3, steps=1024
//  out[b, 2k,   d] = (sum x[b, s..e, d]) / (e-s+1) + 0.006
//  out[b, 2k+1, d] = mean(x[b, 3k:3k+3, d])
//
// Round-7: attack K1 memory-level parallelism + K3 TLP.
//  K1: load ALL 24 rows (96 VGPRs) before any compute/store -> 24 outstanding
//      1KB loads per wave (was ~3, VGPR_Count=24 in R2 showed no hoisting).
//      x read via nontemporal loads (read-once stream).
//  K2: 2-level float4 scan (R6, proven).
//  K3: KT=4 -> 2048 blocks = 32 waves/CU for the latency-bound gather.

constexpr int Bdim  = 8;
constexpr int Nn    = 3072;
constexpr int Dd    = 1024;
constexpr int STEPS = 1024;   // windows
constexpr int CHW   = 8;      // windows per chunk
constexpr int NCH   = 128;    // STEPS / CHW
constexpr int KT    = 4;      // steps per K3 block
constexpr int NKT   = 256;    // STEPS / KT
constexpr int D4    = Dd / 4; // 256 float4 per row
constexpr float EPS = 0.006f;

constexpr size_t WL_E = (size_t)Bdim * STEPS * Dd;        // 32 MB
constexpr size_t P_E  = (size_t)Bdim * NCH * Dd;          //  4 MB

typedef float nat_f4 __attribute__((ext_vector_type(4)));

__device__ __forceinline__ float4 f4add(float4 a, float4 b) {
    return make_float4(a.x + b.x, a.y + b.y, a.z + b.z, a.w + b.w);
}

__device__ __forceinline__ void nt_store(float4 v, float4* p) {
    nat_f4 nv = {v.x, v.y, v.z, v.w};
    __builtin_nontemporal_store(nv, reinterpret_cast<nat_f4*>(p));
}

__device__ __forceinline__ float4 nt_load(const float4* p) {
    nat_f4 nv = __builtin_nontemporal_load(reinterpret_cast<const nat_f4*>(p));
    return make_float4(nv.x, nv.y, nv.z, nv.w);
}

// ---------------- K1: window sums + within-chunk prefix ----------------
__global__ __launch_bounds__(256)
void k1_scan(const float4* __restrict__ x4, float4* __restrict__ out4,
             float4* __restrict__ Wl4, float4* __restrict__ P4) {
    const int t  = threadIdx.x;          // float4 column 0..255
    const int ch = blockIdx.x;           // 0..127
    const int b  = blockIdx.y;           // 0..7
    const int k0 = ch * CHW;
    const int r0 = k0 * 3;

    const float4* xp = x4   + ((size_t)(b * Nn + r0)) * D4 + t;
    float4*       wl = Wl4  + ((size_t)(b * STEPS + k0)) * D4 + t;
    float4*       op = out4 + ((size_t)b * 2 * STEPS) * D4 + t;

    // phase A: issue all 24 loads before any dependent use
    float4 v[3 * CHW];
#pragma unroll
    for (int i = 0; i < 3 * CHW; ++i)
        v[i] = nt_load(&xp[(size_t)i * D4]);

    // phase B: window sums
    float4 w[CHW];
#pragma unroll
    for (int wi = 0; wi < CHW; ++wi)
        w[wi] = f4add(f4add(v[3 * wi], v[3 * wi + 1]), v[3 * wi + 2]);

    // phase C: prefix + stores
    float4 run = make_float4(0.f, 0.f, 0.f, 0.f);
#pragma unroll
    for (int wi = 0; wi < CHW; ++wi) {
        wl[(size_t)wi * D4] = run;                      // exclusive prefix
        float4 wm = make_float4(w[wi].x * (1.f / 3.f), w[wi].y * (1.f / 3.f),
                                w[wi].z * (1.f / 3.f), w[wi].w * (1.f / 3.f));
        nt_store(wm, &op[(size_t)(2 * (k0 + wi) + 1) * D4]);
        run = f4add(run, w[wi]);
    }
    P4[((size_t)b * NCH + ch) * D4 + t] = run;
}

// ---------------- K2: 2-level scan of chunk totals -> exclusive prefix O ----
__global__ __launch_bounds__(256)
void k2_chscan(const float4* __restrict__ P4, float4* __restrict__ O4) {
    __shared__ float4 part[8][33];
    const int cw  = threadIdx.x & 31;          // f4-col within tile
    const int seg = threadIdx.x >> 5;          // 0..7 -> 16 chunks each
    const int col = blockIdx.x * 32 + cw;
    const int b   = blockIdx.y;

    const float4* p = P4 + (size_t)b * NCH * D4 + col;
    float4 v[16];
    float4 sum = make_float4(0.f, 0.f, 0.f, 0.f);
#pragma unroll
    for (int i = 0; i < 16; ++i) {
        v[i] = p[(size_t)(seg * 16 + i) * D4];
        sum = f4add(sum, v[i]);
    }
    part[seg][cw] = sum;
    __syncthreads();
    if (threadIdx.x < 32) {
        float4 run = make_float4(0.f, 0.f, 0.f, 0.f);
#pragma unroll
        for (int s = 0; s < 8; ++s) {
            float4 t2 = part[s][threadIdx.x];
            part[s][threadIdx.x] = run;
            run = f4add(run, t2);
        }
    }
    __syncthreads();
    float4 run = part[seg][cw];
    float4* o = O4 + (size_t)b * (NCH + 1) * D4 + col;
#pragma unroll
    for (int i = 0; i < 16; ++i) {
        o[(size_t)(seg * 16 + i) * D4] = run;
        run = f4add(run, v[i]);
    }
    if (seg == 7) o[(size_t)NCH * D4] = run;   // grand total = c[N]
}

// ---------------- K3: gather segment means ----------------
__global__ __launch_bounds__(256)
void k3_gather(const float4* __restrict__ x4, const float4* __restrict__ Wl4,
               const float4* __restrict__ O4, const int* __restrict__ graph,
               float4* __restrict__ out4) {
    __shared__ int gbuf[2 * KT];
    const int t  = threadIdx.x;
    const int kt = blockIdx.x;
    const int b  = blockIdx.y;

    const int* gs = graph + ((size_t)(b * STEPS + kt * KT)) * 2;
    if (t < 2 * KT) gbuf[t] = gs[t];
    __syncthreads();

    const float4* xb = x4  + (size_t)b * Nn * D4 + t;
    const float4* wl = Wl4 + (size_t)b * STEPS * D4 + t;
    const float4* oc = O4  + (size_t)b * (NCH + 1) * D4 + t;
    float4*       ob = out4 + (size_t)b * 2 * STEPS * D4 + t;

#pragma unroll
    for (int j = 0; j < KT; ++j) {
        int s = gbuf[2 * j];
        int e = gbuf[2 * j + 1];

        int m1 = s / 3, r1 = s - 3 * m1;            // m1 <= 1023
        float4 cs = f4add(oc[(size_t)(m1 >> 3) * D4], wl[(size_t)m1 * D4]);
        if (r1 > 0) cs = f4add(cs, xb[(size_t)(3 * m1) * D4]);
        if (r1 > 1) cs = f4add(cs, xb[(size_t)(3 * m1 + 1) * D4]);

        int ie = e + 1;                             // 1..N
        float4 ce;
        if (ie == Nn) {
            ce = oc[(size_t)NCH * D4];
        } else {
            int m2 = ie / 3, r2 = ie - 3 * m2;
            ce = f4add(oc[(size_t)(m2 >> 3) * D4], wl[(size_t)m2 * D4]);
            if (r2 > 0) ce = f4add(ce, xb[(size_t)(3 * m2) * D4]);
            if (r2 > 1) ce = f4add(ce, xb[(size_t)(3 * m2 + 1) * D4]);
        }

        float inv = 1.f / (float)(e - s + 1);
        float4 res = make_float4((ce.x - cs.x) * inv + EPS,
                                 (ce.y - cs.y) * inv + EPS,
                                 (ce.z - cs.z) * inv + EPS,
                                 (ce.w - cs.w) * inv + EPS);
        int k = kt * KT + j;
        nt_store(res, &ob[(size_t)(2 * k) * D4]);   // even output row
    }
}

extern "C" void kernel_launch(void* const* d_in, const int* in_sizes, int n_in,
                              void* d_out, int out_size, void* d_ws, size_t ws_size,
                              hipStream_t stream) {
    const float* x     = (const float*)d_in[0];
    const int*   graph = (const int*)d_in[1];
    float*       out   = (float*)d_out;

    float* Wl = (float*)d_ws;
    float* P  = Wl + WL_E;
    float* O  = P + P_E;

    dim3 g1(NCH, Bdim);          // (128, 8) = 1024 blocks
    k1_scan<<<g1, 256, 0, stream>>>((const float4*)x, (float4*)out,
                                    (float4*)Wl, (float4*)P);
    dim3 g2(D4 / 32, Bdim);      // (8, 8) = 64 blocks
    k2_chscan<<<g2, 256, 0, stream>>>((const float4*)P, (float4*)O);
    dim3 g3(NKT, Bdim);          // (256, 8) = 2048 blocks -> 32 waves/CU
    k3_gather<<<g3, 256, 0, stream>>>((const float4*)x, (const float4*)Wl,
                                      (const float4*)O, graph, (float4*)out);
}

// Round 8
// 192.629 us; speedup vs baseline: 1.1449x; 1.0262x over previous
//
#include <hip/hip_runtime.h>

// GraphPooling: B=8, N=3072, D=1024, POOL=3, steps=1024
//  out[b, 2k,   d] = (sum x[b, s..e, d]) / (e-s+1) + 0.006
//  out[b, 2k+1, d] = mean(x[b, 3k:3k+3, d])
//
// Round-8: branchless, fully-batched K3.
//  - KT=2, graph read as one uniform int4 (cache broadcast; no LDS, no sync)
//  - all 17 float4 loads per thread issued before any combine; clamped
//    always-valid addresses; residuals/end-case via selects, not branches
//  K1 (R7: 24-row batched nt loads) and K2 (2-level f4 scan) unchanged.

constexpr int Bdim  = 8;
constexpr int Nn    = 3072;
constexpr int Dd    = 1024;
constexpr int STEPS = 1024;   // windows
constexpr int CHW   = 8;      // windows per chunk
constexpr int NCH   = 128;    // STEPS / CHW
constexpr int KT    = 2;      // steps per K3 block
constexpr int NKT   = 512;    // STEPS / KT
constexpr int D4    = Dd / 4; // 256 float4 per row
constexpr float EPS = 0.006f;

constexpr size_t WL_E = (size_t)Bdim * STEPS * Dd;        // 32 MB
constexpr size_t P_E  = (size_t)Bdim * NCH * Dd;          //  4 MB

typedef float nat_f4 __attribute__((ext_vector_type(4)));

__device__ __forceinline__ float4 f4add(float4 a, float4 b) {
    return make_float4(a.x + b.x, a.y + b.y, a.z + b.z, a.w + b.w);
}

__device__ __forceinline__ float4 f4sel(bool c, float4 a, float4 b) {
    return make_float4(c ? a.x : b.x, c ? a.y : b.y,
                       c ? a.z : b.z, c ? a.w : b.w);
}

__device__ __forceinline__ void nt_store(float4 v, float4* p) {
    nat_f4 nv = {v.x, v.y, v.z, v.w};
    __builtin_nontemporal_store(nv, reinterpret_cast<nat_f4*>(p));
}

__device__ __forceinline__ float4 nt_load(const float4* p) {
    nat_f4 nv = __builtin_nontemporal_load(reinterpret_cast<const nat_f4*>(p));
    return make_float4(nv.x, nv.y, nv.z, nv.w);
}

// ---------------- K1: window sums + within-chunk prefix ----------------
__global__ __launch_bounds__(256)
void k1_scan(const float4* __restrict__ x4, float4* __restrict__ out4,
             float4* __restrict__ Wl4, float4* __restrict__ P4) {
    const int t  = threadIdx.x;          // float4 column 0..255
    const int ch = blockIdx.x;           // 0..127
    const int b  = blockIdx.y;           // 0..7
    const int k0 = ch * CHW;
    const int r0 = k0 * 3;

    const float4* xp = x4   + ((size_t)(b * Nn + r0)) * D4 + t;
    float4*       wl = Wl4  + ((size_t)(b * STEPS + k0)) * D4 + t;
    float4*       op = out4 + ((size_t)b * 2 * STEPS) * D4 + t;

    // phase A: issue all 24 loads before any dependent use
    float4 v[3 * CHW];
#pragma unroll
    for (int i = 0; i < 3 * CHW; ++i)
        v[i] = nt_load(&xp[(size_t)i * D4]);

    // phase B: window sums
    float4 w[CHW];
#pragma unroll
    for (int wi = 0; wi < CHW; ++wi)
        w[wi] = f4add(f4add(v[3 * wi], v[3 * wi + 1]), v[3 * wi + 2]);

    // phase C: prefix + stores
    float4 run = make_float4(0.f, 0.f, 0.f, 0.f);
#pragma unroll
    for (int wi = 0; wi < CHW; ++wi) {
        wl[(size_t)wi * D4] = run;                      // exclusive prefix
        float4 wm = make_float4(w[wi].x * (1.f / 3.f), w[wi].y * (1.f / 3.f),
                                w[wi].z * (1.f / 3.f), w[wi].w * (1.f / 3.f));
        nt_store(wm, &op[(size_t)(2 * (k0 + wi) + 1) * D4]);
        run = f4add(run, w[wi]);
    }
    P4[((size_t)b * NCH + ch) * D4 + t] = run;
}

// ---------------- K2: 2-level scan of chunk totals -> exclusive prefix O ----
__global__ __launch_bounds__(256)
void k2_chscan(const float4* __restrict__ P4, float4* __restrict__ O4) {
    __shared__ float4 part[8][33];
    const int cw  = threadIdx.x & 31;          // f4-col within tile
    const int seg = threadIdx.x >> 5;          // 0..7 -> 16 chunks each
    const int col = blockIdx.x * 32 + cw;
    const int b   = blockIdx.y;

    const float4* p = P4 + (size_t)b * NCH * D4 + col;
    float4 v[16];
    float4 sum = make_float4(0.f, 0.f, 0.f, 0.f);
#pragma unroll
    for (int i = 0; i < 16; ++i) {
        v[i] = p[(size_t)(seg * 16 + i) * D4];
        sum = f4add(sum, v[i]);
    }
    part[seg][cw] = sum;
    __syncthreads();
    if (threadIdx.x < 32) {
        float4 run = make_float4(0.f, 0.f, 0.f, 0.f);
#pragma unroll
        for (int s = 0; s < 8; ++s) {
            float4 t2 = part[s][threadIdx.x];
            part[s][threadIdx.x] = run;
            run = f4add(run, t2);
        }
    }
    __syncthreads();
    float4 run = part[seg][cw];
    float4* o = O4 + (size_t)b * (NCH + 1) * D4 + col;
#pragma unroll
    for (int i = 0; i < 16; ++i) {
        o[(size_t)(seg * 16 + i) * D4] = run;
        run = f4add(run, v[i]);
    }
    if (seg == 7) o[(size_t)NCH * D4] = run;   // grand total = c[N]
}

// ---------------- K3: branchless batched gather ----------------
__global__ __launch_bounds__(256)
void k3_gather(const float4* __restrict__ x4, const float4* __restrict__ Wl4,
               const float4* __restrict__ O4, const int* __restrict__ graph,
               float4* __restrict__ out4) {
    const int t  = threadIdx.x;
    const int kt = blockIdx.x;                 // 0..511
    const int b  = blockIdx.y;

    // 2 steps' (s,e) as one uniform 16B load (broadcast; no LDS, no sync)
    const int4 g2 = *reinterpret_cast<const int4*>(
        graph + ((size_t)(b * STEPS + kt * KT)) * 2);
    const int sA[KT] = {g2.x, g2.z};
    const int eA[KT] = {g2.y, g2.w};

    const float4* xb = x4  + (size_t)b * Nn * D4 + t;
    const float4* wl = Wl4 + (size_t)b * STEPS * D4 + t;
    const float4* oc = O4  + (size_t)b * (NCH + 1) * D4 + t;
    float4*       ob = out4 + (size_t)b * 2 * STEPS * D4 + t;

    // ---- issue ALL loads before any combine ----
    float4 o1[KT], w1[KT], xs0[KT], xs1[KT];
    float4 o2[KT], w2[KT], xe0[KT], xe1[KT];
    int r1[KT], r2[KT], ieA[KT];
    float4 tot = oc[(size_t)NCH * D4];          // grand-total row (L2/L3-warm)
#pragma unroll
    for (int u = 0; u < KT; ++u) {
        int s  = sA[u];
        int m1 = s / 3;          r1[u] = s - 3 * m1;       // m1 <= 1023
        o1[u]  = oc[(size_t)(m1 >> 3) * D4];
        w1[u]  = wl[(size_t)m1 * D4];
        xs0[u] = xb[(size_t)(3 * m1) * D4];
        xs1[u] = xb[(size_t)(3 * m1 + 1) * D4];

        int ie = eA[u] + 1;      ieA[u] = ie;              // 1..3072
        int m2 = ie / 3;         r2[u] = ie - 3 * m2;
        int mc = m2 < STEPS - 1 ? m2 : STEPS - 1;          // clamp: always valid
        o2[u]  = oc[(size_t)(mc >> 3) * D4];
        w2[u]  = wl[(size_t)mc * D4];
        xe0[u] = xb[(size_t)(3 * mc) * D4];
        xe1[u] = xb[(size_t)(3 * mc + 1) * D4];
    }

    // ---- combine + store ----
    const float4 z4 = make_float4(0.f, 0.f, 0.f, 0.f);
#pragma unroll
    for (int u = 0; u < KT; ++u) {
        float4 cs = f4add(f4add(o1[u], w1[u]),
                          f4add(f4sel(r1[u] > 0, xs0[u], z4),
                                f4sel(r1[u] > 1, xs1[u], z4)));
        float4 ceN = f4add(f4add(o2[u], w2[u]),
                           f4add(f4sel(r2[u] > 0, xe0[u], z4),
                                 f4sel(r2[u] > 1, xe1[u], z4)));
        float4 ce = f4sel(ieA[u] == Nn, tot, ceN);

        float inv = 1.f / (float)(eA[u] - sA[u] + 1);
        float4 res = make_float4((ce.x - cs.x) * inv + EPS,
                                 (ce.y - cs.y) * inv + EPS,
                                 (ce.z - cs.z) * inv + EPS,
                                 (ce.w - cs.w) * inv + EPS);
        int k = kt * KT + u;
        nt_store(res, &ob[(size_t)(2 * k) * D4]);   // even output row
    }
}

extern "C" void kernel_launch(void* const* d_in, const int* in_sizes, int n_in,
                              void* d_out, int out_size, void* d_ws, size_t ws_size,
                              hipStream_t stream) {
    const float* x     = (const float*)d_in[0];
    const int*   graph = (const int*)d_in[1];
    float*       out   = (float*)d_out;

    float* Wl = (float*)d_ws;
    float* P  = Wl + WL_E;
    float* O  = P + P_E;

    dim3 g1(NCH, Bdim);          // (128, 8) = 1024 blocks
    k1_scan<<<g1, 256, 0, stream>>>((const float4*)x, (float4*)out,
                                    (float4*)Wl, (float4*)P);
    dim3 g2(D4 / 32, Bdim);      // (8, 8) = 64 blocks
    k2_chscan<<<g2, 256, 0, stream>>>((const float4*)P, (float4*)O);
    dim3 g3(NKT, Bdim);          // (512, 8) = 4096 blocks
    k3_gather<<<g3, 256, 0, stream>>>((const float4*)x, (const float4*)Wl,
                                      (const float4*)O, graph, (float4*)out);
}